// Round 1
// baseline (1146.677 us; speedup 1.0000x reference)
//
#include <hip/hip_runtime.h>

#define D128 128

// ---------------- CSR build ----------------

__global__ __launch_bounds__(256) void degree_k(const int* __restrict__ src, const int* __restrict__ dst,
                                                int* deg_c, int* deg_p, int E) {
  int e = blockIdx.x * 256 + threadIdx.x;
  if (e >= E) return;
  atomicAdd(&deg_p[dst[e]], 1);
  atomicAdd(&deg_c[src[e]], 1);
}

// exclusive scan, level 1: each block scans a 2048 chunk, writes block total
__global__ __launch_bounds__(256) void scan1_k(const int* __restrict__ in, int* __restrict__ out,
                                               int* __restrict__ bsum, int n) {
  __shared__ int sh[256];
  int tid = threadIdx.x;
  int base = blockIdx.x * 2048 + tid * 8;
  int v[8]; int s = 0;
#pragma unroll
  for (int u = 0; u < 8; ++u) { int i = base + u; v[u] = (i < n) ? in[i] : 0; s += v[u]; }
  sh[tid] = s; __syncthreads();
#pragma unroll
  for (int o = 1; o < 256; o <<= 1) {
    int t = (tid >= o) ? sh[tid - o] : 0;
    __syncthreads();
    sh[tid] += t;
    __syncthreads();
  }
  int run = sh[tid] - s;
  if (tid == 255) bsum[blockIdx.x] = sh[255];
#pragma unroll
  for (int u = 0; u < 8; ++u) { int i = base + u; if (i < n) out[i] = run; run += v[u]; }
}

// level 2: exclusive scan of block sums in-place (n <= 64), 1 block x 64 threads
__global__ void scan_small_k(int* b, int n) {
  __shared__ int sh[64];
  int tid = threadIdx.x;
  int v = (tid < n) ? b[tid] : 0;
  sh[tid] = v; __syncthreads();
  for (int o = 1; o < 64; o <<= 1) {
    int t = (tid >= o) ? sh[tid - o] : 0;
    __syncthreads();
    sh[tid] += t;
    __syncthreads();
  }
  if (tid < n) b[tid] = sh[tid] - v;
}

// level 3: add block offsets
__global__ __launch_bounds__(256) void scan_add_k(int* out, const int* __restrict__ bsum, int n) {
  int b = blockIdx.x;
  if (b == 0) return;
  int add = bsum[b];
  int base = b * 2048;
  for (int i = threadIdx.x; i < 2048; i += 256) { int idx = base + i; if (idx < n) out[idx] += add; }
}

__global__ __launch_bounds__(256) void fill_k(const int* __restrict__ src, const int* __restrict__ dst,
                                              const int* __restrict__ off_p, const int* __restrict__ off_c,
                                              int* cur_p, int* cur_c, int* adj_p, int* adj_c, int E) {
  int e = blockIdx.x * 256 + threadIdx.x;
  if (e >= E) return;
  int s = src[e], d = dst[e];
  int pp = atomicAdd(&cur_p[d], 1); adj_p[off_p[d] + pp] = s;
  int pc = atomicAdd(&cur_c[s], 1); adj_c[off_c[s] + pc] = d;
}

// ---------------- aggregation: mean of neighbor rows ----------------
// one wave per dst node; lane owns 2 columns (float2) -> 512B coalesced per neighbor

__global__ __launch_bounds__(256) void agg_mean_k(const float* __restrict__ src,
                                                  const int* __restrict__ adj, const int* __restrict__ off,
                                                  const int* __restrict__ deg,
                                                  float* __restrict__ outmean, int Ndst) {
  int v = blockIdx.x * 4 + (threadIdx.x >> 6);
  if (v >= Ndst) return;
  int l2 = (threadIdx.x & 63) * 2;
  int s = off[v], cnt = deg[v];
  float ax = 0.f, ay = 0.f, bx = 0.f, by = 0.f;
  int n = 0;
  for (; n + 2 <= cnt; n += 2) {
    int i0 = adj[s + n], i1 = adj[s + n + 1];
    float2 x0 = *(const float2*)&src[(size_t)i0 * D128 + l2];
    float2 x1 = *(const float2*)&src[(size_t)i1 * D128 + l2];
    ax += x0.x; ay += x0.y; bx += x1.x; by += x1.y;
  }
  if (n < cnt) {
    int i0 = adj[s + n];
    float2 x0 = *(const float2*)&src[(size_t)i0 * D128 + l2];
    ax += x0.x; ay += x0.y;
  }
  float inv = (cnt > 0) ? 1.f / (float)cnt : 0.f;
  float2 m; m.x = (ax + bx) * inv; m.y = (ay + by) * inv;
  *(float2*)&outmean[(size_t)v * D128 + l2] = m;
}

// ---------------- fused SAGE linear: out = relu(mean@Wl^T + hold@Wr^T + b) ----------------
// io_mean doubles as output (row-wise in-place; mean row only read during staging).
// tile: 32 rows x 128 cols, 256 threads, each thread 8 rows x 2 cols.

__global__ __launch_bounds__(256) void gemm_fused_k(float* io_mean, const float* __restrict__ hold,
                                                    const float* __restrict__ Wl, const float* __restrict__ Wr,
                                                    const float* __restrict__ bias, int N) {
  __shared__ float xs[32][256];
  __shared__ float ws[32][128];
  int tid = threadIdx.x;
  int rbase = blockIdx.x * 32;
#pragma unroll
  for (int i = 0; i < 8; ++i) {
    int f = tid + i * 256;        // float4 id over 32x256
    int r = f >> 6;
    int c4 = (f & 63) << 2;
    int rr = rbase + r; if (rr >= N) rr = N - 1;
    const float* sp = (c4 < 128) ? &io_mean[(size_t)rr * D128 + c4]
                                 : &hold[(size_t)rr * D128 + (c4 - 128)];
    *(float4*)&xs[r][c4] = *(const float4*)sp;
  }
  float acc[8][2];
#pragma unroll
  for (int i = 0; i < 8; ++i) { acc[i][0] = 0.f; acc[i][1] = 0.f; }
  int j2 = (tid & 63) * 2;
  int sg = tid >> 6;              // 0..3 -> rows sg*8..sg*8+7

  for (int k0 = 0; k0 < 256; k0 += 32) {
    __syncthreads();
    const float* Wsrc = (k0 < 128) ? Wl : Wr;
    int kb = (k0 < 128) ? k0 : (k0 - 128);
#pragma unroll
    for (int i = 0; i < 4; ++i) {
      int f = tid + i * 256;      // 1024 float4 = 32x128
      int j = f >> 3;             // output col
      int c = (f & 7) << 2;       // kk base
      float4 w = *(const float4*)&Wsrc[j * D128 + kb + c];
      ws[c + 0][j] = w.x; ws[c + 1][j] = w.y; ws[c + 2][j] = w.z; ws[c + 3][j] = w.w;
    }
    __syncthreads();
#pragma unroll
    for (int kk = 0; kk < 32; kk += 4) {
      float2 wv0 = *(float2*)&ws[kk + 0][j2];
      float2 wv1 = *(float2*)&ws[kk + 1][j2];
      float2 wv2 = *(float2*)&ws[kk + 2][j2];
      float2 wv3 = *(float2*)&ws[kk + 3][j2];
#pragma unroll
      for (int i = 0; i < 8; ++i) {
        float4 xv = *(float4*)&xs[sg * 8 + i][k0 + kk];
        acc[i][0] += xv.x * wv0.x + xv.y * wv1.x + xv.z * wv2.x + xv.w * wv3.x;
        acc[i][1] += xv.x * wv0.y + xv.y * wv1.y + xv.z * wv2.y + xv.w * wv3.y;
      }
    }
  }
  float2 bv = *(const float2*)&bias[j2];
#pragma unroll
  for (int i = 0; i < 8; ++i) {
    int rr = rbase + sg * 8 + i;
    if (rr < N) {
      float ox = acc[i][0] + bv.x;
      float oy = acc[i][1] + bv.y;
      ox = ox > 0.f ? ox : 0.f;
      oy = oy > 0.f ? oy : 0.f;
      float2 o; o.x = ox; o.y = oy;
      *(float2*)&io_mean[(size_t)rr * D128 + j2] = o;
    }
  }
}

// ---------------- decoder: z = [hc[row]||hp[col]] . Wd + bd ; also emit x ----------------

__global__ __launch_bounds__(256) void decoder_k(const float* __restrict__ hc, const float* __restrict__ hp,
                                                 const int* __restrict__ row, const int* __restrict__ col,
                                                 const float* __restrict__ Wd, const float* __restrict__ bd,
                                                 float* __restrict__ out, int EL) {
  int e = blockIdx.x * 4 + (threadIdx.x >> 6);
  if (e >= EL) return;
  int l2 = (threadIdx.x & 63) * 2;
  int r = row[e], c = col[e];
  float2 a = *(const float2*)&hc[(size_t)r * D128 + l2];
  float2 b = *(const float2*)&hp[(size_t)c * D128 + l2];
  float2 w0 = *(const float2*)&Wd[l2];
  float2 w1 = *(const float2*)&Wd[128 + l2];
  float p = a.x * w0.x + a.y * w0.y + b.x * w1.x + b.y * w1.y;
#pragma unroll
  for (int m = 1; m < 64; m <<= 1) p += __shfl_xor(p, m, 64);
  float* xo = out + EL + (size_t)e * 256;
  *(float2*)&xo[l2] = a;
  *(float2*)&xo[128 + l2] = b;
  if ((threadIdx.x & 63) == 0) out[e] = p + bd[0];
}

// ---------------- host ----------------

extern "C" void kernel_launch(void* const* d_in, const int* in_sizes, int n_in,
                              void* d_out, int out_size, void* d_ws, size_t ws_size,
                              hipStream_t stream) {
  const float* x_chem = (const float*)d_in[0];
  const float* x_prot = (const float*)d_in[1];
  const float* Wl = (const float*)d_in[2];
  const float* bl = (const float*)d_in[3];
  const float* Wr = (const float*)d_in[4];
  const float* Wd = (const float*)d_in[5];
  const float* bd = (const float*)d_in[6];
  const int* src = (const int*)d_in[7];
  const int* dst = (const int*)d_in[8];
  const int* row = (const int*)d_in[9];
  const int* col = (const int*)d_in[10];

  int NC = in_sizes[0] / D128;
  int NP = in_sizes[1] / D128;
  int E  = in_sizes[7];
  int EL = in_sizes[9];
  float* out = (float*)d_out;

  // workspace layout
  char* w = (char*)d_ws;
  size_t szC = (size_t)NC * D128 * sizeof(float);
  size_t szP = (size_t)NP * D128 * sizeof(float);
  float* bufC0 = (float*)w; w += szC;
  float* bufC1 = (float*)w; w += szC;
  float* bufP0 = (float*)w; w += szP;
  float* bufP1 = (float*)w; w += szP;
  int* deg_p = (int*)w; w += (size_t)NP * 4;
  int* deg_c = (int*)w; w += (size_t)NC * 4;
  int* cur_p = (int*)w; w += (size_t)NP * 4;
  int* cur_c = (int*)w; w += (size_t)NC * 4;
  int* off_p = (int*)w; w += (size_t)NP * 4;
  int* off_c = (int*)w; w += (size_t)NC * 4;
  int* bsP   = (int*)w; w += 64 * 4;
  int* bsC   = (int*)w; w += 64 * 4;
  int* adj_p = (int*)w; w += (size_t)E * 4;
  int* adj_c = (int*)w; w += (size_t)E * 4;
  if ((size_t)(w - (char*)d_ws) > ws_size) return;  // insufficient scratch; fail visibly

  // zero deg_p, deg_c, cur_p, cur_c (contiguous)
  hipMemsetAsync(deg_p, 0, (size_t)(2 * NP + 2 * NC) * 4, stream);

  int gE = (E + 255) / 256;
  degree_k<<<gE, 256, 0, stream>>>(src, dst, deg_c, deg_p, E);

  int nbP = (NP + 2047) / 2048;
  int nbC = (NC + 2047) / 2048;
  scan1_k<<<nbP, 256, 0, stream>>>(deg_p, off_p, bsP, NP);
  scan_small_k<<<1, 64, 0, stream>>>(bsP, nbP);
  scan_add_k<<<nbP, 256, 0, stream>>>(off_p, bsP, NP);
  scan1_k<<<nbC, 256, 0, stream>>>(deg_c, off_c, bsC, NC);
  scan_small_k<<<1, 64, 0, stream>>>(bsC, nbC);
  scan_add_k<<<nbC, 256, 0, stream>>>(off_c, bsC, NC);

  fill_k<<<gE, 256, 0, stream>>>(src, dst, off_p, off_c, cur_p, cur_c, adj_p, adj_c, E);

  const float* hc = x_chem;
  const float* hp = x_prot;
  for (int l = 0; l < 3; ++l) {
    float* nc  = (l & 1) ? bufC1 : bufC0;
    float* np_ = (l & 1) ? bufP1 : bufP0;
    // aggregate means (both read old hc/hp)
    agg_mean_k<<<(NP + 3) / 4, 256, 0, stream>>>(hc, adj_p, off_p, deg_p, np_, NP);
    agg_mean_k<<<(NC + 3) / 4, 256, 0, stream>>>(hp, adj_c, off_c, deg_c, nc, NC);
    // fused linear + bias + relu, in-place over the mean buffer
    const float* WlP = Wl + (size_t)(l * 2 + 0) * D128 * D128;
    const float* WrP = Wr + (size_t)(l * 2 + 0) * D128 * D128;
    const float* blP = bl + (size_t)(l * 2 + 0) * D128;
    const float* WlC = Wl + (size_t)(l * 2 + 1) * D128 * D128;
    const float* WrC = Wr + (size_t)(l * 2 + 1) * D128 * D128;
    const float* blC = bl + (size_t)(l * 2 + 1) * D128;
    gemm_fused_k<<<(NP + 31) / 32, 256, 0, stream>>>(np_, hp, WlP, WrP, blP, NP);
    gemm_fused_k<<<(NC + 31) / 32, 256, 0, stream>>>(nc, hc, WlC, WrC, blC, NC);
    hc = nc; hp = np_;
  }

  decoder_k<<<(EL + 3) / 4, 256, 0, stream>>>(hc, hp, row, col, Wd, bd, out, EL);
}

// Round 2
// 615.470 us; speedup vs baseline: 1.8631x; 1.8631x over previous
//
#include <hip/hip_runtime.h>

#define D128 128

typedef __attribute__((ext_vector_type(8))) short bf16x8;
typedef __attribute__((ext_vector_type(4))) float f32x4;

__device__ __forceinline__ unsigned short f2b(float f) {
  union { float f; unsigned int u; } x; x.f = f;
  unsigned int r = x.u + 0x7fffu + ((x.u >> 16) & 1u);
  return (unsigned short)(r >> 16);
}

#define GLD16(gp, lp) __builtin_amdgcn_global_load_lds( \
    (const __attribute__((address_space(1))) void*)(gp), \
    (__attribute__((address_space(3))) void*)(lp), 16, 0, 0)

// ---------------- conversions ----------------

__global__ __launch_bounds__(256) void cvt_f2b_k(const float* __restrict__ in,
                                                 unsigned short* __restrict__ o, int n4) {
  int i = blockIdx.x * 256 + threadIdx.x;
  int stride = gridDim.x * 256;
  for (; i < n4; i += stride) {
    float4 f = ((const float4*)in)[i];
    uint2 u;
    u.x = (unsigned int)f2b(f.x) | ((unsigned int)f2b(f.y) << 16);
    u.y = (unsigned int)f2b(f.z) | ((unsigned int)f2b(f.w) << 16);
    ((uint2*)o)[i] = u;
  }
}

// Wcat[slice][j][k0..255] = concat(Wl[slice][j][:], Wr[slice][j][:]) in bf16
__global__ __launch_bounds__(256) void cvt_w_k(const float* __restrict__ Wl, const float* __restrict__ Wr,
                                               unsigned short* __restrict__ Wcat) {
  int t = blockIdx.x * 256 + threadIdx.x;   // 6*128*256 = 196608
  if (t >= 6 * 128 * 256) return;
  int slice = t >> 15;
  int j = (t >> 8) & 127;
  int k = t & 255;
  float v = (k < 128) ? Wl[(size_t)slice * 16384 + j * 128 + k]
                      : Wr[(size_t)slice * 16384 + j * 128 + (k - 128)];
  Wcat[t] = f2b(v);
}

// ---------------- CSR build ----------------

__global__ __launch_bounds__(256) void degree_k(const int* __restrict__ src, const int* __restrict__ dst,
                                                int* deg_c, int* deg_p, int E) {
  int e = blockIdx.x * 256 + threadIdx.x;
  if (e >= E) return;
  atomicAdd(&deg_p[dst[e]], 1);
  atomicAdd(&deg_c[src[e]], 1);
}

__global__ __launch_bounds__(256) void scan1_k(const int* __restrict__ in, int* __restrict__ out,
                                               int* __restrict__ bsum, int n) {
  __shared__ int sh[256];
  int tid = threadIdx.x;
  int base = blockIdx.x * 2048 + tid * 8;
  int v[8]; int s = 0;
#pragma unroll
  for (int u = 0; u < 8; ++u) { int i = base + u; v[u] = (i < n) ? in[i] : 0; s += v[u]; }
  sh[tid] = s; __syncthreads();
#pragma unroll
  for (int o = 1; o < 256; o <<= 1) {
    int t = (tid >= o) ? sh[tid - o] : 0;
    __syncthreads();
    sh[tid] += t;
    __syncthreads();
  }
  int run = sh[tid] - s;
  if (tid == 255) bsum[blockIdx.x] = sh[255];
#pragma unroll
  for (int u = 0; u < 8; ++u) { int i = base + u; if (i < n) out[i] = run; run += v[u]; }
}

__global__ void scan_small_k(int* b, int n) {
  __shared__ int sh[64];
  int tid = threadIdx.x;
  int v = (tid < n) ? b[tid] : 0;
  sh[tid] = v; __syncthreads();
  for (int o = 1; o < 64; o <<= 1) {
    int t = (tid >= o) ? sh[tid - o] : 0;
    __syncthreads();
    sh[tid] += t;
    __syncthreads();
  }
  if (tid < n) b[tid] = sh[tid] - v;
}

__global__ __launch_bounds__(256) void scan_add_k(int* out, const int* __restrict__ bsum, int n) {
  int b = blockIdx.x;
  if (b == 0) return;
  int add = bsum[b];
  int base = b * 2048;
  for (int i = threadIdx.x; i < 2048; i += 256) { int idx = base + i; if (idx < n) out[idx] += add; }
}

__global__ __launch_bounds__(256) void fill_k(const int* __restrict__ src, const int* __restrict__ dst,
                                              const int* __restrict__ off_p, const int* __restrict__ off_c,
                                              int* cur_p, int* cur_c, int* adj_p, int* adj_c, int E) {
  int e = blockIdx.x * 256 + threadIdx.x;
  if (e >= E) return;
  int s = src[e], d = dst[e];
  int pp = atomicAdd(&cur_p[d], 1); adj_p[off_p[d] + pp] = s;
  int pc = atomicAdd(&cur_c[s], 1); adj_c[off_c[s] + pc] = d;
}

// ---------------- aggregation: bf16 gather, f32 accum, bf16 mean out ----------------

__global__ __launch_bounds__(256) void agg_mean_b_k(const unsigned short* __restrict__ src,
                                                    const int* __restrict__ adj, const int* __restrict__ off,
                                                    const int* __restrict__ deg,
                                                    unsigned short* __restrict__ outmean, int Ndst) {
  int v = blockIdx.x * 4 + (threadIdx.x >> 6);
  if (v >= Ndst) return;
  int l2 = (threadIdx.x & 63) * 2;
  int s = off[v], cnt = deg[v];
  float ax = 0.f, ay = 0.f, bx = 0.f, by = 0.f;
  int n = 0;
  for (; n + 2 <= cnt; n += 2) {
    int i0 = adj[s + n], i1 = adj[s + n + 1];
    unsigned int u0 = *(const unsigned int*)&src[(size_t)i0 * D128 + l2];
    unsigned int u1 = *(const unsigned int*)&src[(size_t)i1 * D128 + l2];
    ax += __uint_as_float(u0 << 16); ay += __uint_as_float(u0 & 0xffff0000u);
    bx += __uint_as_float(u1 << 16); by += __uint_as_float(u1 & 0xffff0000u);
  }
  if (n < cnt) {
    int i0 = adj[s + n];
    unsigned int u0 = *(const unsigned int*)&src[(size_t)i0 * D128 + l2];
    ax += __uint_as_float(u0 << 16); ay += __uint_as_float(u0 & 0xffff0000u);
  }
  float inv = (cnt > 0) ? 1.f / (float)cnt : 0.f;
  unsigned int pk = (unsigned int)f2b((ax + bx) * inv) | ((unsigned int)f2b((ay + by) * inv) << 16);
  *(unsigned int*)&outmean[(size_t)v * D128 + l2] = pk;
}

// ---------------- MFMA GEMM: io = relu(concat(io,hold) @ Wcat^T + bias) ----------------
// 128x128 tile, K=256 in 4 steps of 64; 4 waves (2x2), mfma_f32_16x16x32_bf16.
// LDS tiles hold the XOR-swizzled layout (chunk ^= row&7) via pre-swizzled
// global_load_lds source addresses; ds_read_b128 fragment reads are then 2-way (free).

__global__ __launch_bounds__(256) void gemm_mfma_k(unsigned short* __restrict__ io_mean,
                                                   const unsigned short* __restrict__ hold,
                                                   const unsigned short* __restrict__ Wcat,
                                                   const float* __restrict__ bias, int N) {
  __shared__ unsigned short As[128 * 64];
  __shared__ unsigned short Bs[128 * 64];
  const int tid = threadIdx.x;
  const int w = tid >> 6, lane = tid & 63;
  const int wr = w >> 1, wc = w & 1;
  const int rbase = blockIdx.x * 128;
  const int l15 = lane & 15, chi = lane >> 4;

  f32x4 acc[4][4];
#pragma unroll
  for (int m = 0; m < 4; ++m)
#pragma unroll
    for (int n = 0; n < 4; ++n) acc[m][n] = (f32x4){0.f, 0.f, 0.f, 0.f};

  for (int ks = 0; ks < 4; ++ks) {
    const int k0 = ks * 64;
    const unsigned short* Xsrc = (k0 < 128) ? io_mean : hold;
    const int kb = k0 & 127;
    if (ks) __syncthreads();
#pragma unroll
    for (int q = 0; q < 4; ++q) {
      const int ibase = w * 256 + q * 64;
      const int i = ibase + lane;
      const int r = i >> 3;                 // tile row (A) / output col (B)
      const int cg = (i & 7) ^ (r & 7);     // pre-swizzled source chunk
      int rr = rbase + r; if (rr >= N) rr = N - 1;
      const unsigned short* gp = Xsrc + (size_t)rr * D128 + kb + cg * 8;
      GLD16(gp, (char*)As + ibase * 16);
      const unsigned short* gw = Wcat + (size_t)r * 256 + k0 + cg * 8;
      GLD16(gw, (char*)Bs + ibase * 16);
    }
    __syncthreads();
#pragma unroll
    for (int kk = 0; kk < 2; ++kk) {
      bf16x8 a[4], b[4];
      const int c = kk * 4 + chi;
#pragma unroll
      for (int m = 0; m < 4; ++m) {
        const int r = wr * 64 + m * 16 + l15;
        a[m] = *(const bf16x8*)((const char*)As + (r * 8 + (c ^ (r & 7))) * 16);
      }
#pragma unroll
      for (int n = 0; n < 4; ++n) {
        const int j = wc * 64 + n * 16 + l15;
        b[n] = *(const bf16x8*)((const char*)Bs + (j * 8 + (c ^ (j & 7))) * 16);
      }
#pragma unroll
      for (int m = 0; m < 4; ++m)
#pragma unroll
        for (int n = 0; n < 4; ++n)
          acc[m][n] = __builtin_amdgcn_mfma_f32_16x16x32_bf16(a[m], b[n], acc[m][n], 0, 0, 0);
    }
  }

#pragma unroll
  for (int n = 0; n < 4; ++n) {
    const int col = wc * 64 + n * 16 + l15;
    const float bv = bias[col];
#pragma unroll
    for (int m = 0; m < 4; ++m) {
      const int rb2 = rbase + wr * 64 + m * 16 + chi * 4;
#pragma unroll
      for (int q = 0; q < 4; ++q) {
        const int row = rb2 + q;
        if (row < N) {
          float v = acc[m][n][q] + bv;
          v = v > 0.f ? v : 0.f;
          io_mean[(size_t)row * D128 + col] = f2b(v);
        }
      }
    }
  }
}

// ---------------- decoder ----------------

__global__ __launch_bounds__(256) void decoder_b_k(const unsigned short* __restrict__ hc,
                                                   const unsigned short* __restrict__ hp,
                                                   const int* __restrict__ row, const int* __restrict__ col,
                                                   const float* __restrict__ Wd, const float* __restrict__ bd,
                                                   float* __restrict__ out, int EL) {
  int e = blockIdx.x * 4 + (threadIdx.x >> 6);
  if (e >= EL) return;
  int lane = threadIdx.x & 63;
  int l2 = lane * 2;
  int r = row[e], c = col[e];
  unsigned int ua = *(const unsigned int*)&hc[(size_t)r * D128 + l2];
  unsigned int ub = *(const unsigned int*)&hp[(size_t)c * D128 + l2];
  float ax = __uint_as_float(ua << 16), ay = __uint_as_float(ua & 0xffff0000u);
  float bx = __uint_as_float(ub << 16), by = __uint_as_float(ub & 0xffff0000u);
  float2 w0 = *(const float2*)&Wd[l2];
  float2 w1 = *(const float2*)&Wd[128 + l2];
  float p = ax * w0.x + ay * w0.y + bx * w1.x + by * w1.y;
#pragma unroll
  for (int m = 1; m < 64; m <<= 1) p += __shfl_xor(p, m, 64);
  float* xo = out + EL + (size_t)e * 256;
  float2 A; A.x = ax; A.y = ay;
  float2 B; B.x = bx; B.y = by;
  *(float2*)&xo[l2] = A;
  *(float2*)&xo[128 + l2] = B;
  if (lane == 0) out[e] = p + bd[0];
}

// ---------------- host ----------------

extern "C" void kernel_launch(void* const* d_in, const int* in_sizes, int n_in,
                              void* d_out, int out_size, void* d_ws, size_t ws_size,
                              hipStream_t stream) {
  const float* x_chem = (const float*)d_in[0];
  const float* x_prot = (const float*)d_in[1];
  const float* Wl = (const float*)d_in[2];
  const float* bl = (const float*)d_in[3];
  const float* Wr = (const float*)d_in[4];
  const float* Wd = (const float*)d_in[5];
  const float* bd = (const float*)d_in[6];
  const int* src = (const int*)d_in[7];
  const int* dst = (const int*)d_in[8];
  const int* row = (const int*)d_in[9];
  const int* col = (const int*)d_in[10];

  int NC = in_sizes[0] / D128;
  int NP = in_sizes[1] / D128;
  int E  = in_sizes[7];
  int EL = in_sizes[9];
  float* out = (float*)d_out;

  // workspace layout (bf16 buffers as ushort)
  char* w = (char*)d_ws;
  size_t szC = (size_t)NC * D128 * 2;
  size_t szP = (size_t)NP * D128 * 2;
  unsigned short* xc_bf = (unsigned short*)w; w += szC;
  unsigned short* xp_bf = (unsigned short*)w; w += szP;
  unsigned short* bufC0 = (unsigned short*)w; w += szC;
  unsigned short* bufC1 = (unsigned short*)w; w += szC;
  unsigned short* bufP0 = (unsigned short*)w; w += szP;
  unsigned short* bufP1 = (unsigned short*)w; w += szP;
  unsigned short* Wcat  = (unsigned short*)w; w += (size_t)6 * 128 * 256 * 2;
  int* deg_p = (int*)w; w += (size_t)NP * 4;
  int* deg_c = (int*)w; w += (size_t)NC * 4;
  int* cur_p = (int*)w; w += (size_t)NP * 4;
  int* cur_c = (int*)w; w += (size_t)NC * 4;
  int* off_p = (int*)w; w += (size_t)NP * 4;
  int* off_c = (int*)w; w += (size_t)NC * 4;
  int* bsP   = (int*)w; w += 64 * 4;
  int* bsC   = (int*)w; w += 64 * 4;
  int* adj_p = (int*)w; w += (size_t)E * 4;
  int* adj_c = (int*)w; w += (size_t)E * 4;
  if ((size_t)(w - (char*)d_ws) > ws_size) return;

  // conversions
  int n4c = NC * D128 / 4, n4p = NP * D128 / 4;
  cvt_f2b_k<<<2048, 256, 0, stream>>>(x_chem, xc_bf, n4c);
  cvt_f2b_k<<<(n4p + 255) / 256, 256, 0, stream>>>(x_prot, xp_bf, n4p);
  cvt_w_k<<<768, 256, 0, stream>>>(Wl, Wr, Wcat);

  // CSR build
  hipMemsetAsync(deg_p, 0, (size_t)(2 * NP + 2 * NC) * 4, stream);
  int gE = (E + 255) / 256;
  degree_k<<<gE, 256, 0, stream>>>(src, dst, deg_c, deg_p, E);
  int nbP = (NP + 2047) / 2048;
  int nbC = (NC + 2047) / 2048;
  scan1_k<<<nbP, 256, 0, stream>>>(deg_p, off_p, bsP, NP);
  scan_small_k<<<1, 64, 0, stream>>>(bsP, nbP);
  scan_add_k<<<nbP, 256, 0, stream>>>(off_p, bsP, NP);
  scan1_k<<<nbC, 256, 0, stream>>>(deg_c, off_c, bsC, NC);
  scan_small_k<<<1, 64, 0, stream>>>(bsC, nbC);
  scan_add_k<<<nbC, 256, 0, stream>>>(off_c, bsC, NC);
  fill_k<<<gE, 256, 0, stream>>>(src, dst, off_p, off_c, cur_p, cur_c, adj_p, adj_c, E);

  const unsigned short* hc = xc_bf;
  const unsigned short* hp = xp_bf;
  for (int l = 0; l < 3; ++l) {
    unsigned short* nc  = (l & 1) ? bufC1 : bufC0;
    unsigned short* np_ = (l & 1) ? bufP1 : bufP0;
    agg_mean_b_k<<<(NP + 3) / 4, 256, 0, stream>>>(hc, adj_p, off_p, deg_p, np_, NP);
    agg_mean_b_k<<<(NC + 3) / 4, 256, 0, stream>>>(hp, adj_c, off_c, deg_c, nc, NC);
    const unsigned short* WcP = Wcat + (size_t)(l * 2 + 0) * 128 * 256;
    const unsigned short* WcC = Wcat + (size_t)(l * 2 + 1) * 128 * 256;
    const float* blP = bl + (size_t)(l * 2 + 0) * D128;
    const float* blC = bl + (size_t)(l * 2 + 1) * D128;
    gemm_mfma_k<<<(NP + 127) / 128, 256, 0, stream>>>(np_, hp, WcP, blP, NP);
    gemm_mfma_k<<<(NC + 127) / 128, 256, 0, stream>>>(nc, hc, WcC, blC, NC);
    hc = nc; hp = np_;
  }

  decoder_b_k<<<(EL + 3) / 4, 256, 0, stream>>>(hc, hp, row, col, Wd, bd, out, EL);
}